// Round 4
// baseline (7221.285 us; speedup 1.0000x reference)
//
#include <hip/hip_runtime.h>
#include <hip/hip_bf16.h>

typedef __hip_bfloat16 bf16;

#define NV 110592           // 48^3
#define NVLL 110592ull

// mixed-dtype input load: f=1 -> buffer is fp32, f=0 -> buffer is bf16
__device__ inline float ldmix(const void* p, size_t i, int f){
  return f ? ((const float*)p)[i] : __bfloat162float(((const bf16*)p)[i]);
}

// ---------------- workspace layout (BYTES), total = 96 MiB ----------------
// [0, 1,572,864)             : SMALL (pools, attn outs, stats, fp32 weights, flag)
// [1,572,864, 44,040,192)    : A = i1 bf16 (21,233,664 e), later h1 (14,155,776 e)
// [44,040,192, 100,663,296)  : B = i2 bf16 (21,233,664 e) overlaid by E bf16 (28,311,552 e),
//                              later h2 (14,155,776 e)
static const size_t BOFF_A  = 1572864;
static const size_t BOFF_B  = 44040192;
// small-region float offsets
#define SM_P1   0
#define SM_P2   41472
#define SM_PKV  82944
#define SM_A1   124416
#define SM_A2   165888
#define SM_ST   207360
#define SM_W    208064
#define SM_FL   392848   // 1 float flag (region budget 393,216 floats)

// fp32 weight region offsets (floats)
#define W_UPW   0
#define W_UPB   16384
#define W_WF    16416
#define W_BF    19488
#define W_W1    19536
#define W_B1    21072
#define W_W2    21120
#define W_B2    22656
#define W_W3    22704
#define W_B3    25008
#define W_W4    25056
#define W_B4    27360
#define W_GNG   27408
#define W_GNB   27456
#define W_ATT   27504    // 2 sets of 9408 (wq2304,bq48,wk,bk,wv,bv,wo,bo)
#define W_WFIN  46320
#define W_BFIN  52464
#define W_C0W   52528
#define W_C0B   107824
#define W_C1W   107856
#define W_C1B   135504
#define W_TOTAL 135536
// folded (device-computed) parity weights: x0 never materialized
#define W_W1P   135536   // [8 par][48 o][64 c]
#define W_B1F   160112   // [48]
#define W_WFP   160160   // [8 par][48 o][64 c]
#define W_BFF   184736   // [48]
#define W_TOT2  184784

// ---------------- dtype detect: bf16-interp max |v| > 1e3  =>  data is fp32 ----------
__global__ __launch_bounds__(256) void k_detect(const void* xe, float* __restrict__ flag){
  const bf16* p = (const bf16*)xe;
  int tid = threadIdx.x;
  float mx = 0.f;
  for(int i=tid;i<8192;i+=256){
    float v = fabsf(__bfloat162float(p[i]));
    if(!(v==v)) v = 1e30f;            // NaN -> huge
    mx = fmaxf(mx, v);
  }
  #pragma unroll
  for(int s=32;s>=1;s>>=1) mx = fmaxf(mx, __shfl_xor(mx,s));
  __shared__ float red[4];
  if((tid&63)==0) red[tid>>6] = mx;
  __syncthreads();
  if(tid==0){
    float m = fmaxf(fmaxf(red[0],red[1]), fmaxf(red[2],red[3]));
    flag[0] = (m > 1e3f) ? 1.f : 0.f;
  }
}

// ---------------- zero stats ----------------
__global__ __launch_bounds__(256) void k_zero(float* __restrict__ st){
  int i = blockIdx.x*256 + threadIdx.x;
  if(i < 704) st[i] = 0.f;
}

// ---------------- weight prep: (bf16|fp32) -> fp32 ----------------
struct PtrTab { const void* p[36]; };
__device__ const int g_seg[36] = {16384,32,3072,48,1536,48,1536,48,2304,48,2304,48,48,48,
  2304,48,2304,48,2304,48,2304,48,2304,48,2304,48,2304,48,2304,48,6144,64,55296,32,27648,32};

__global__ __launch_bounds__(256) void k_prep(PtrTab t, float* __restrict__ W, const float* __restrict__ flag){
  const int f = (int)flag[0];
  int i = blockIdx.x*256 + threadIdx.x;
  if(i >= W_TOTAL) return;
  int rem = i;
  for(int s=0;s<36;s++){
    int sz = g_seg[s];
    if(rem < sz){ W[i] = ldmix(t.p[s], rem, f); return; }
    rem -= sz;
  }
}

// ---------------- fold deconv into consumers: per-parity combined matrices -------------
__global__ __launch_bounds__(256) void k_fold(float* __restrict__ W){
  int i = blockIdx.x*256 + threadIdx.x;
  const float* upw = W + W_UPW;
  const float* upb = W + W_UPB;
  if(i < 49152){
    int which = i / 24576;            // 0 -> W1P, 1 -> WFP
    int r = i % 24576;
    int par = r / 3072; int o = (r/64)%48; int c = r%64;
    float acc = 0.f;
    for(int m=0;m<32;m++){
      float wm = which ? W[W_WF + o*64 + 32 + m] : W[W_W1 + o*32 + m];
      acc += wm * upw[c*256 + m*8 + par];
    }
    W[(which ? W_WFP : W_W1P) + par*3072 + o*64 + c] = acc;
  } else if(i < 49248){
    int j = i - 49152;
    int which = j / 48; int o = j % 48;
    float acc = which ? W[W_BF + o] : W[W_B1 + o];
    for(int m=0;m<32;m++){
      float wm = which ? W[W_WF + o*64 + 32 + m] : W[W_W1 + o*32 + m];
      acc += wm * upb[m];
    }
    W[(which ? W_BFF : W_B1F) + o] = acc;
  }
}

// ---------------- i1 pre-conv: folded deconv+conv1x1(w1), GN stats set0 ----------------
__global__ __launch_bounds__(256) void k_i1pre(const void* __restrict__ x, const float* __restrict__ W,
    bf16* __restrict__ out, float* __restrict__ stats_out, const float* __restrict__ flag)
{
  const int f = (int)flag[0];
  const int v = blockIdx.x*256 + threadIdx.x;
  const int b = blockIdx.y;
  const int xx = v%48, yy = (v/48)%48, zz = v/2304;
  const int par = ((zz&1)<<2) | ((yy&1)<<1) | (xx&1);
  const int vh = (zz>>1)*576 + (yy>>1)*24 + (xx>>1);
  float xr[64];
  #pragma unroll
  for(int c=0;c<64;c++) xr[c] = ldmix(x, (size_t)(b*64+c)*13824 + vh, f);
  const float* wp = W + W_W1P + par*3072;
  const float* bp = W + W_B1F;
  float ls = 0.f, lss = 0.f;
  #pragma unroll
  for(int o=0;o<48;o++){
    float acc = bp[o];
    #pragma unroll
    for(int c=0;c<64;c++) acc += wp[o*64+c]*xr[c];
    out[((size_t)(b*48+o))*NVLL + v] = __float2bfloat16(acc);
    ls += acc; lss += acc*acc;
    if((o&7)==7){
      #pragma unroll
      for(int sh=32;sh>=1;sh>>=1){ ls += __shfl_down(ls,sh); lss += __shfl_down(lss,sh); }
      if((threadIdx.x & 63)==0){
        int g = o>>3;
        atomicAdd(&stats_out[b*6+g], ls);
        atomicAdd(&stats_out[24 + b*6+g], lss);
      }
      ls = 0.f; lss = 0.f;
    }
  }
}

// ---------------- conv1x1 (+optional fused GN+leaky on input) + GN stats on output -----
// MIXIN: input is a raw harness buffer (dtype per flag); else internal bf16 buffer
template<int CIN, bool GNIN, bool MIXIN>
__global__ __launch_bounds__(256) void k_c1gn(const void* in, const float* __restrict__ W48,
    const float* __restrict__ bias, const float* __restrict__ gamma, const float* __restrict__ beta,
    const float* __restrict__ stats_in, int set_in,
    bf16* out, float* stats_out, int set_out, const float* __restrict__ flag)
{
  const int f = MIXIN ? (int)flag[0] : 0;
  const int v = blockIdx.x*256 + threadIdx.x;
  const int b = blockIdx.y;
  float m[6], rs[6];
  if constexpr(GNIN){
    const float invN = 1.0f/(8.0f*(float)NV);
    #pragma unroll
    for(int g=0; g<6; g++){
      float s  = stats_in[set_in*48 + b*6 + g];
      float ss = stats_in[set_in*48 + 24 + b*6 + g];
      float mm = s*invN;
      float var = ss*invN - mm*mm;
      m[g] = mm; rs[g] = rsqrtf(var + 1e-5f);
    }
  }
  float inv[CIN];
  #pragma unroll
  for(int c=0;c<CIN;c++){
    float xv = MIXIN ? ldmix(in, ((size_t)(b*CIN+c))*NVLL + v, f)
                     : __bfloat162float(((const bf16*)in)[((size_t)(b*CIN+c))*NVLL + v]);
    if constexpr(GNIN){
      int g = c>>3;
      xv = (xv - m[g])*rs[g]*gamma[c] + beta[c];
      xv = xv < 0.f ? 0.1f*xv : xv;
    }
    inv[c] = xv;
  }
  float ls = 0.f, lss = 0.f;
  #pragma unroll
  for(int o=0;o<48;o++){
    float acc = bias[o];
    #pragma unroll
    for(int c=0;c<CIN;c++) acc += W48[o*CIN+c]*inv[c];
    out[((size_t)(b*48+o))*NVLL + v] = __float2bfloat16(acc);
    ls += acc; lss += acc*acc;
    if((o&7)==7){
      #pragma unroll
      for(int sh=32;sh>=1;sh>>=1){ ls += __shfl_down(ls,sh); lss += __shfl_down(lss,sh); }
      if((threadIdx.x & 63)==0){
        int g = o>>3;
        atomicAdd(&stats_out[set_out*48 + b*6+g], ls);
        atomicAdd(&stats_out[set_out*48 + 24 + b*6+g], lss);
      }
      ls = 0.f; lss = 0.f;
    }
  }
}

// ---------------- GN apply + leaky(0.1) in place (bf16 buffer) ----------------
__global__ __launch_bounds__(256) void k_gn_apply(bf16* buf, const float* __restrict__ stats, int set,
    const float* __restrict__ gamma, const float* __restrict__ beta)
{
  size_t i = (size_t)blockIdx.x*256 + threadIdx.x;   // exact grid: 4*48*NV
  int c = (int)((i/NVLL)%48);
  int b = (int)(i/(NVLL*48));
  int g = c>>3;
  const float invN = 1.0f/(8.0f*(float)NV);
  float s  = stats[set*48 + b*6+g];
  float ss = stats[set*48 + 24 + b*6+g];
  float m = s*invN; float var = ss*invN - m*m; float rs = rsqrtf(var + 1e-5f);
  float xv = __bfloat162float(buf[i]);
  xv = (xv - m)*rs*gamma[c] + beta[c];
  buf[i] = __float2bfloat16(xv < 0.f ? 0.1f*xv : xv);
}

// ---------------- adaptive max+avg pool 48^3 -> 6^3 on bf16 (wave per cell) ------------
__global__ __launch_bounds__(256) void k_pool(const bf16* __restrict__ s0, const bf16* __restrict__ s1,
    float* __restrict__ d0, float* __restrict__ d1)
{
  int wid = threadIdx.x>>6, lane = threadIdx.x&63;
  int cell = blockIdx.x*4 + wid;                 // < 4*48*216
  const bf16* src = blockIdx.y==0 ? s0 : s1;
  float*      dst = blockIdx.y==0 ? d0 : d1;
  int n = cell % 216; int bc = cell/216;
  int cz = n/36, cy = (n/6)%6, cx = n%6;
  int dz = lane>>3, dy = lane&7;
  const bf16* row = src + ((size_t)bc*48 + (cz*8+dz))*2304 + (cy*8+dy)*48 + cx*8;
  float mx = -1e30f, sm = 0.f;
  #pragma unroll
  for(int k=0;k<8;k++){ float vv = __bfloat162float(row[k]); mx = fmaxf(mx, vv); sm += vv; }
  #pragma unroll
  for(int s=32;s>=1;s>>=1){ mx = fmaxf(mx, __shfl_xor(mx,s)); sm += __shfl_xor(sm,s); }
  if(lane==0) dst[(size_t)bc*216 + n] = mx + sm*(1.f/512.f);
}

// ---------------- fused conv1x1(concat(xe, folded-x0)) + pool -> pkv -------------------
__global__ __launch_bounds__(512) void k_poolfuse(const void* __restrict__ xe, const void* __restrict__ x,
    const float* __restrict__ W, float* __restrict__ pkv, const float* __restrict__ flag)
{
  const int f = (int)flag[0];
  const int cell = blockIdx.x % 216;
  const int b = blockIdx.x / 216;
  const int tid = threadIdx.x;
  const int cz = cell/36, cy = (cell/6)%6, cx = cell%6;
  const int dz = tid>>6, dy = (tid>>3)&7, dx = tid&7;
  const int gz = cz*8+dz, gy = cy*8+dy, gx = cx*8+dx;
  const size_t voff = (size_t)gz*2304 + gy*48 + gx;
  const int par = ((gz&1)<<2) | ((gy&1)<<1) | (gx&1);
  const int vh = (gz>>1)*576 + (gy>>1)*24 + (gx>>1);
  float xev[32], xrv[64];
  #pragma unroll
  for(int c=0;c<32;c++) xev[c] = ldmix(xe, ((size_t)(b*32+c))*NVLL + voff, f);
  #pragma unroll
  for(int c=0;c<64;c++) xrv[c] = ldmix(x, (size_t)(b*64+c)*13824 + vh, f);
  const float* wf  = W + W_WF;
  const float* wfp = W + W_WFP + par*3072;
  const float* bff = W + W_BFF;
  __shared__ float rmax[8][48];
  __shared__ float rsum[8][48];
  const int wid = tid>>6, lane = tid&63;
  #pragma unroll
  for(int o=0;o<48;o++){
    float acc = bff[o];
    #pragma unroll
    for(int c=0;c<32;c++) acc += wf[o*64+c]*xev[c];
    #pragma unroll
    for(int c=0;c<64;c++) acc += wfp[o*64+c]*xrv[c];
    float mx = acc, sm = acc;
    #pragma unroll
    for(int s=32;s>=1;s>>=1){ mx = fmaxf(mx, __shfl_xor(mx,s)); sm += __shfl_xor(sm,s); }
    if(lane==0){ rmax[wid][o] = mx; rsum[wid][o] = sm; }
  }
  __syncthreads();
  if(tid < 48){
    float mx = rmax[0][tid], sm = rsum[0][tid];
    #pragma unroll
    for(int w2=1;w2<8;w2++){ mx = fmaxf(mx, rmax[w2][tid]); sm += rsum[w2][tid]; }
    pkv[((size_t)(b*48+tid))*216 + cell] = mx + sm*(1.f/512.f);
  }
}

// ---------------- linear cross-attention (one block per (attn, batch)) ----------------
__global__ __launch_bounds__(256) void k_attn(const float* __restrict__ p1, const float* __restrict__ p2,
    const float* __restrict__ pkv, const float* __restrict__ W, float* __restrict__ a1, float* __restrict__ a2)
{
  const int which = blockIdx.x, b = blockIdx.y;
  const float* wb = W + W_ATT + which*9408;
  const float* wq = wb;        const float* bq = wb+2304;
  const float* wk = wb+2352;   const float* bk = wb+4656;
  const float* wv = wb+4704;   const float* bv = wb+7008;
  const float* wo = wb+7056;   const float* bo = wb+9360;
  const float* q   = which ? p2 : p1;
  float*       aout= which ? a2 : a1;
  const float* kvb = pkv + (size_t)b*48*216;
  const float* qb  = q   + (size_t)b*48*216;
  __shared__ float kh[216*48];     // 40.5 KB
  __shared__ float ctx[288];
  const int tid = threadIdx.x;

  if(tid < 216){
    float kvr[48];
    #pragma unroll
    for(int c=0;c<48;c++) kvr[c] = kvb[c*216 + tid];
    #pragma unroll
    for(int o=0;o<48;o++){
      float acc = bk[o];
      #pragma unroll
      for(int c=0;c<48;c++) acc += kvr[c]*wk[o*48+c];
      kh[tid*48+o] = acc;
    }
  }
  __syncthreads();
  if(tid < 48){
    float mx = -1e30f;
    for(int n=0;n<216;n++) mx = fmaxf(mx, kh[n*48+tid]);
    float s = 0.f;
    for(int n=0;n<216;n++){ float e = __expf(kh[n*48+tid]-mx); kh[n*48+tid] = e; s += e; }
    float inv = 1.f/s;
    for(int n=0;n<216;n++) kh[n*48+tid] *= inv;
  }
  __syncthreads();
  if(tid < 48){
    int h = tid/6, e = tid%6;
    float cacc[6] = {0,0,0,0,0,0};
    for(int n=0;n<216;n++){
      float vh = bv[h*6+e];
      #pragma unroll
      for(int c=0;c<48;c++) vh += kvb[c*216+n]*wv[(h*6+e)*48+c];
      #pragma unroll
      for(int d=0;d<6;d++) cacc[d] += kh[n*48 + h*6+d]*vh;
    }
    #pragma unroll
    for(int d=0;d<6;d++) ctx[(h*6+d)*6+e] = cacc[d];
  }
  __syncthreads();
  if(tid < 216){
    int n = tid;
    float qr[48];
    #pragma unroll
    for(int c=0;c<48;c++) qr[c] = qb[c*216 + n];
    float qh[48];
    #pragma unroll
    for(int o=0;o<48;o++){
      float acc = bq[o];
      #pragma unroll
      for(int c=0;c<48;c++) acc += qr[c]*wq[o*48+c];
      qh[o] = acc;
    }
    #pragma unroll
    for(int h=0;h<8;h++){
      float mx = qh[h*6];
      #pragma unroll
      for(int d=1;d<6;d++) mx = fmaxf(mx, qh[h*6+d]);
      float s = 0.f;
      #pragma unroll
      for(int d=0;d<6;d++){ float e = __expf(qh[h*6+d]-mx); qh[h*6+d] = e; s += e; }
      float inv = 1.f/s;
      #pragma unroll
      for(int d=0;d<6;d++) qh[h*6+d] *= inv;
    }
    float ov[48];
    #pragma unroll
    for(int h=0;h<8;h++){
      #pragma unroll
      for(int e=0;e<6;e++){
        float acc = 0.f;
        #pragma unroll
        for(int d=0;d<6;d++) acc += qh[h*6+d]*ctx[(h*6+d)*6+e];
        ov[h*6+e] = acc;
      }
    }
    #pragma unroll
    for(int o=0;o<48;o++){
      float acc = bo[o];
      #pragma unroll
      for(int c=0;c<48;c++) acc += ov[c]*wo[o*48+c];
      aout[((size_t)(b*48+o))*216 + n] = acc;
    }
  }
}

// --------- upsample(a)->sigmoid->gate i1/i2 -> conv1x1 (96->64) -> E, ONE BATCH --------
// E overlays i2's region; launched per-batch in REVERSE order (b=3..0). Collisions are
// same-voxel same-thread (reads before writes) or already-dead later batches.
__device__ inline void interp1(int u, int& i0, int& i1, float& t){
  float pos = u * (5.0f/47.0f);
  float f = floorf(pos);
  i0 = (int)f; if(i0 > 5) i0 = 5;
  i1 = i0+1 > 5 ? 5 : i0+1;
  t = pos - f; if(t < 0.f) t = 0.f; if(t > 1.f) t = 1.f;
}

__global__ __launch_bounds__(256) void k_fuse_out(int b, const bf16* __restrict__ i1b, const bf16* i2b,
    const float* __restrict__ a1, const float* __restrict__ a2,
    const float* __restrict__ wfin, const float* __restrict__ bfin, bf16* E)
{
  const int v = blockIdx.x*256 + threadIdx.x;
  const int x = v % 48, y = (v/48) % 48, z = v/2304;
  int xi0,xi1,yi0,yi1,zi0,zi1; float xt,yt,zt;
  interp1(x,xi0,xi1,xt); interp1(y,yi0,yi1,yt); interp1(z,zi0,zi1,zt);
  int off[8]; float cw[8];
  off[0]=zi0*36+yi0*6+xi0; cw[0]=(1-zt)*(1-yt)*(1-xt);
  off[1]=zi0*36+yi0*6+xi1; cw[1]=(1-zt)*(1-yt)*xt;
  off[2]=zi0*36+yi1*6+xi0; cw[2]=(1-zt)*yt*(1-xt);
  off[3]=zi0*36+yi1*6+xi1; cw[3]=(1-zt)*yt*xt;
  off[4]=zi1*36+yi0*6+xi0; cw[4]=zt*(1-yt)*(1-xt);
  off[5]=zi1*36+yi0*6+xi1; cw[5]=zt*(1-yt)*xt;
  off[6]=zi1*36+yi1*6+xi0; cw[6]=zt*yt*(1-xt);
  off[7]=zi1*36+yi1*6+xi1; cw[7]=zt*yt*xt;

  float o1[48], o2[48];
  #pragma unroll
  for(int c=0;c<48;c++){
    const float* ap = a1 + ((size_t)(b*48+c))*216;
    float s = 0.f;
    #pragma unroll
    for(int k=0;k<8;k++) s += cw[k]*ap[off[k]];
    s = 1.f/(1.f + __expf(-s));
    o1[c] = s * __bfloat162float(i1b[((size_t)(b*48+c))*NVLL + v]);
  }
  #pragma unroll
  for(int c=0;c<48;c++){
    const float* ap = a2 + ((size_t)(b*48+c))*216;
    float s = 0.f;
    #pragma unroll
    for(int k=0;k<8;k++) s += cw[k]*ap[off[k]];
    s = 1.f/(1.f + __expf(-s));
    o2[c] = s * __bfloat162float(i2b[((size_t)(b*48+c))*NVLL + v]);
  }
  #pragma unroll
  for(int o=0;o<64;o++){
    float acc = bfin[o];
    #pragma unroll
    for(int c=0;c<48;c++) acc += wfin[o*96+c]*o1[c];
    #pragma unroll
    for(int c=0;c<48;c++) acc += wfin[o*96+48+c]*o2[c];
    E[((size_t)(b*64+o))*NVLL + v] = __float2bfloat16(acc);
  }
}

// ---------------- conv3x3x3 (pad 1), optional fused IN+leaky(0.01) on input,
//                  fp32 IN stats (sum,sumsq) on output via atomics, bf16 out ------------
template<int CIN, bool NORM>
__global__ __launch_bounds__(512) void k_conv3(const bf16* __restrict__ in, const float* __restrict__ wt,
    const float* __restrict__ bias, const float* __restrict__ stats, int sIn,
    bf16* __restrict__ outp, float* __restrict__ stato, int sOut)
{
  const int b = blockIdx.y;
  const int tile = blockIdx.x;                     // 0..215 (6x6x6 tiles of 8^3)
  const int z0 = (tile/36)*8, y0 = ((tile/6)%6)*8, x0 = (tile%6)*8;
  const int tid = threadIdx.x;
  const int tz = tid>>6, ty = (tid>>3)&7, tx = tid&7;
  __shared__ float sm[1000];                       // 10x10x10 halo tile
  float acc[32];
  #pragma unroll
  for(int oc=0;oc<32;oc++) acc[oc] = bias[oc];

  for(int c=0;c<CIN;c++){
    float m = 0.f, rs = 0.f;
    if constexpr(NORM){
      const float invN = 1.f/(float)NV;
      float s  = stats[sIn + b*32 + c];
      float ss = stats[sIn + 128 + b*32 + c];
      m = s*invN; float var = ss*invN - m*m; rs = rsqrtf(var + 1e-5f);
    }
    __syncthreads();
    for(int i=tid;i<1000;i+=512){
      int lz = i/100, r = i - lz*100, ly = r/10, lx = r - ly*10;
      int gz = z0+lz-1, gy = y0+ly-1, gx = x0+lx-1;
      float vv = 0.f;
      if(gz>=0 && gz<48 && gy>=0 && gy<48 && gx>=0 && gx<48){
        vv = __bfloat162float(in[(size_t)(b*CIN+c)*NVLL + gz*2304 + gy*48 + gx]);
        if constexpr(NORM){ vv = (vv-m)*rs; vv = vv<0.f ? 0.01f*vv : vv; }
      }
      sm[i] = vv;
    }
    __syncthreads();
    float nb[27];
    #pragma unroll
    for(int dz=0;dz<3;dz++)
      #pragma unroll
      for(int dy=0;dy<3;dy++)
        #pragma unroll
        for(int dx=0;dx<3;dx++)
          nb[dz*9+dy*3+dx] = sm[(tz+dz)*100 + (ty+dy)*10 + (tx+dx)];
    const float* wc = wt + c*27;
    #pragma unroll
    for(int oc=0;oc<32;oc++){
      const float* w = wc + oc*CIN*27;
      #pragma unroll
      for(int k=0;k<27;k++) acc[oc] += w[k]*nb[k];
    }
  }

  const size_t obase = (size_t)b*32*NVLL + (z0+tz)*2304 + (y0+ty)*48 + (x0+tx);
  #pragma unroll
  for(int oc=0;oc<32;oc++) outp[obase + (size_t)oc*NVLL] = __float2bfloat16(acc[oc]);

  #pragma unroll
  for(int oc=0;oc<32;oc++){
    float s = acc[oc], ss = s*s;
    #pragma unroll
    for(int sh=32;sh>=1;sh>>=1){ s += __shfl_down(s,sh); ss += __shfl_down(ss,sh); }
    if((tid&63)==0){
      atomicAdd(&stato[sOut + b*32+oc], s);
      atomicAdd(&stato[sOut + 128 + b*32+oc], ss);
    }
  }
}

// ---------------- final instance-norm + leaky(0.01): h2(bf16) -> d_out (flag dtype) ----
__global__ __launch_bounds__(256) void k_in_final(const bf16* __restrict__ G, const float* __restrict__ stats,
    int set, void* out, const float* __restrict__ flag)
{
  const int f = (int)flag[0];
  int i = blockIdx.x*256 + threadIdx.x;            // exact grid: 4*32*NV
  int c = (i/NV)%32; int b = i/(NV*32);
  const float invN = 1.f/(float)NV;
  float s  = stats[set + b*32 + c];
  float ss = stats[set + 128 + b*32 + c];
  float m = s*invN; float var = ss*invN - m*m; float rs = rsqrtf(var + 1e-5f);
  float xv = (__bfloat162float(G[i])-m)*rs;
  xv = xv < 0.f ? 0.01f*xv : xv;
  if(f) ((float*)out)[i] = xv;
  else  ((bf16*)out)[i]  = __float2bfloat16(xv);
}

// ==========================================================================
extern "C" void kernel_launch(void* const* d_in, const int* in_sizes, int n_in,
                              void* d_out, int out_size, void* d_ws, size_t ws_size,
                              hipStream_t stream)
{
  (void)in_sizes; (void)n_in; (void)out_size; (void)ws_size;
  char* base = (char*)d_ws;
  const void* x  = d_in[0];
  const void* xe = d_in[1];

  float* SM  = (float*)base;
  float* P1  = SM + SM_P1;
  float* P2  = SM + SM_P2;
  float* PKV = SM + SM_PKV;
  float* A1  = SM + SM_A1;
  float* A2  = SM + SM_A2;
  float* ST  = SM + SM_ST;
  float* W   = SM + SM_W;
  float* FL  = SM + SM_FL;
  bf16*  A   = (bf16*)(base + BOFF_A);   // i1, later h1
  bf16*  Bb  = (bf16*)(base + BOFF_B);   // i2, later E (overlay), later h2
  bf16*  E   = Bb;

  k_detect<<<1, 256, 0, stream>>>(xe, FL);
  k_zero<<<3, 256, 0, stream>>>(ST);

  PtrTab pt;
  for(int i=0;i<36;i++) pt.p[i] = d_in[i+2];
  k_prep<<<(W_TOTAL+255)/256, 256, 0, stream>>>(pt, W, FL);
  k_fold<<<193, 256, 0, stream>>>(W);

  const float* gam = W + W_GNG;
  const float* bet = W + W_GNB;

  // i1 branch: folded deconv+conv(w1) -> A (+stats set0); conv(w3) fused GN(set0) -> A (+set1); apply set1
  k_i1pre<<<dim3(432,4), 256, 0, stream>>>(x, W, A, ST, FL);
  k_c1gn<48,true ,false><<<dim3(432,4),256,0,stream>>>(A, W+W_W3, W+W_B3, gam, bet, ST, 0, A, ST, 1, FL);
  k_gn_apply<<<21233664/256, 256, 0, stream>>>(A, ST, 1, gam, bet);

  // i2 branch: xe (raw input, flag dtype) -> B
  k_c1gn<32,false,true ><<<dim3(432,4),256,0,stream>>>(xe, W+W_W2, W+W_B2, gam, bet, ST, 0, Bb, ST, 2, FL);
  k_c1gn<48,true ,false><<<dim3(432,4),256,0,stream>>>(Bb, W+W_W4, W+W_B4, gam, bet, ST, 2, Bb, ST, 3, FL);
  k_gn_apply<<<21233664/256, 256, 0, stream>>>(Bb, ST, 3, gam, bet);

  // pools: p1<-i1, p2<-i2 ; pkv <- fused conv1x1(concat(xe, folded x0)) + pool
  k_pool<<<dim3(10368,2), 256, 0, stream>>>(A, Bb, P1, P2);
  k_poolfuse<<<864, 512, 0, stream>>>(xe, x, W, PKV, FL);

  // attentions
  k_attn<<<dim3(2,4), 256, 0, stream>>>(P1, P2, PKV, W, A1, A2);

  // fuse -> E (overlays i2), reverse batch order for overlay safety
  for(int b=3;b>=0;b--)
    k_fuse_out<<<432, 256, 0, stream>>>(b, A, Bb, A1, A2, W+W_WFIN, W+W_BFIN, E);

  // conv3x3x3 #1 (64->32): E -> h1 (@A), IN stats at 192
  k_conv3<64,false><<<dim3(216,4), 512, 0, stream>>>(E, W+W_C0W, W+W_C0B, ST, 0, A, ST, 192);
  // conv3x3x3 #2 (32->32), fused IN(192)+leaky(0.01) on input: h1 -> h2 (@Bb, E dead), stats at 448
  k_conv3<32,true ><<<dim3(216,4), 512, 0, stream>>>(A, W+W_C1W, W+W_C1B, ST, 192, Bb, ST, 448);

  // final IN + leaky(0.01): h2 -> d_out (dtype per flag)
  k_in_final<<<14155776/256, 256, 0, stream>>>(Bb, ST, 448, d_out, FL);
}

// Round 5
// 4196.537 us; speedup vs baseline: 1.7208x; 1.7208x over previous
//
#include <hip/hip_runtime.h>
#include <hip/hip_bf16.h>

typedef __hip_bfloat16 bf16;
typedef __attribute__((ext_vector_type(8))) short short8x;
typedef __attribute__((ext_vector_type(4))) float f32x4;

#define NV 110592           // 48^3
#define NVLL 110592ull

__device__ inline float ldmix(const void* p, size_t i, int f){
  return f ? ((const float*)p)[i] : __bfloat162float(((const bf16*)p)[i]);
}

// ---------------- workspace layout (BYTES), total <= 96 MiB ----------------
// [0, 2,621,440)   : SMALL (pools, attn, stats, fp32 weights, packed bf16 frags, flag)
// [2,621,440,  45,088,768) : O1 = i1/o1 NHWC bf16 [4][NV][48]; later h1(b=1..3) NHWC
// [45,088,768, 87,556,096) : O2 = i2/o2 NHWC bf16 [4][NV][48]; later h2(b) NCHW slabs
// [87,556,096, 94,633,984) : SPARE = h1(b=0) NHWC bf16 [NV][32]
static const size_t BOFF_O1 = 2621440;
static const size_t BOFF_O2 = 45088768;
static const size_t BOFF_SP = 87556096;
static const size_t SLOT48  = 10616832;   // bytes of one batch of 48ch bf16
// small-region float offsets
#define SM_P1   0
#define SM_P2   41472
#define SM_PKV  82944
#define SM_A1   124416
#define SM_A2   165888
#define SM_ST   207360
#define SM_W    208064

// fp32 weight region offsets (floats, relative to W)
#define W_UPW   0
#define W_UPB   16384
#define W_WF    16416
#define W_BF    19488
#define W_W1    19536
#define W_B1    21072
#define W_W2    21120
#define W_B2    22656
#define W_W3    22704
#define W_B3    25008
#define W_W4    25056
#define W_B4    27360
#define W_GNG   27408
#define W_GNB   27456
#define W_ATT   27504
#define W_WFIN  46320
#define W_BFIN  52464
#define W_C0W   52528
#define W_C0B   107824
#define W_C1W   107856
#define W_C1B   135504
#define W_TOTAL 135536
// folded parity weights (deconv fused into consumers)
#define W_W1P   135536   // [8][48][64]
#define W_B1F   160112
#define W_WFP   160160   // [8][48][64]
#define W_BFF   184736
// conv1' folded weights (C0W o Wfin) + per-tap bias + packed bf16 fragments
#define W_WP    184784   // fp32 [32 oc][96 k][27 tap]
#define W_TB    267728   // fp32 [27 tap][32 oc]
#define W_WB1   268592   // bf16[82944] = frag order [tap][kt][nt][64][8]
#define W_WB2   310064   // bf16[27648]
#define W_TOTF  323888
#define SM_FL   531952   // flag (after SM_W + W_TOTF = 208064+323888)

// ---------------- dtype detect ----------------
__global__ __launch_bounds__(256) void k_detect(const void* xe, float* __restrict__ flag){
  const bf16* p = (const bf16*)xe;
  int tid = threadIdx.x;
  float mx = 0.f;
  for(int i=tid;i<8192;i+=256){
    float v = fabsf(__bfloat162float(p[i]));
    if(!(v==v)) v = 1e30f;
    mx = fmaxf(mx, v);
  }
  #pragma unroll
  for(int s=32;s>=1;s>>=1) mx = fmaxf(mx, __shfl_xor(mx,s));
  __shared__ float red[4];
  if((tid&63)==0) red[tid>>6] = mx;
  __syncthreads();
  if(tid==0){
    float m = fmaxf(fmaxf(red[0],red[1]), fmaxf(red[2],red[3]));
    flag[0] = (m > 1e3f) ? 1.f : 0.f;
  }
}

__global__ __launch_bounds__(256) void k_zero(float* __restrict__ st){
  int i = blockIdx.x*256 + threadIdx.x;
  if(i < 704) st[i] = 0.f;
}

// ---------------- weight prep: (bf16|fp32) -> fp32 ----------------
struct PtrTab { const void* p[36]; };
__device__ const int g_seg[36] = {16384,32,3072,48,1536,48,1536,48,2304,48,2304,48,48,48,
  2304,48,2304,48,2304,48,2304,48,2304,48,2304,48,2304,48,2304,48,6144,64,55296,32,27648,32};

__global__ __launch_bounds__(256) void k_prep(PtrTab t, float* __restrict__ W, const float* __restrict__ flag){
  const int f = (int)flag[0];
  int i = blockIdx.x*256 + threadIdx.x;
  if(i >= W_TOTAL) return;
  int rem = i;
  for(int s=0;s<36;s++){
    int sz = g_seg[s];
    if(rem < sz){ W[i] = ldmix(t.p[s], rem, f); return; }
    rem -= sz;
  }
}

// ---------------- fold deconv into consumers ----------------
__global__ __launch_bounds__(256) void k_fold(float* __restrict__ W){
  int i = blockIdx.x*256 + threadIdx.x;
  const float* upw = W + W_UPW;
  const float* upb = W + W_UPB;
  if(i < 49152){
    int which = i / 24576;
    int r = i % 24576;
    int par = r / 3072; int o = (r/64)%48; int c = r%64;
    float acc = 0.f;
    for(int m=0;m<32;m++){
      float wm = which ? W[W_WF + o*64 + 32 + m] : W[W_W1 + o*32 + m];
      acc += wm * upw[c*256 + m*8 + par];
    }
    W[(which ? W_WFP : W_W1P) + par*3072 + o*64 + c] = acc;
  } else if(i < 49248){
    int j = i - 49152;
    int which = j / 48; int o = j % 48;
    float acc = which ? W[W_BF + o] : W[W_B1 + o];
    for(int m=0;m<32;m++){
      float wm = which ? W[W_WF + o*64 + 32 + m] : W[W_W1 + o*32 + m];
      acc += wm * upb[m];
    }
    W[(which ? W_BFF : W_B1F) + o] = acc;
  }
}

// ---------------- fold Wfin into conv#1: W'[oc][k96][tap] and tb[tap][oc] --------------
__global__ __launch_bounds__(256) void k_fold2(float* __restrict__ W){
  int i = blockIdx.x*256 + threadIdx.x;
  if(i < 82944){
    int tap = i%27; int k = (i/27)%96; int oc = i/(27*96);
    float acc = 0.f;
    for(int m=0;m<64;m++) acc += W[W_C0W + oc*1728 + m*27 + tap] * W[W_WFIN + m*96 + k];
    W[W_WP + i] = acc;
  } else if(i < 83808){
    int j = i - 82944;
    int tap = j/32, oc = j%32;
    float acc = 0.f;
    for(int m=0;m<64;m++) acc += W[W_C0W + oc*1728 + m*27 + tap] * W[W_BFIN + m];
    W[W_TB + tap*32 + oc] = acc;
  }
}

// ---------------- pack B-fragments (bf16): [tap][kt][nt][lane][8] ----------------
__global__ __launch_bounds__(256) void k_packb1(float* __restrict__ W){
  int i = blockIdx.x*256 + threadIdx.x;
  if(i >= 82944) return;
  int j = i&7; int lane = (i>>3)&63; int frag = i>>9;
  int nt = frag&1; int tkt = frag>>1; int kt = tkt%3; int tap = tkt/3;
  int oc = nt*16 + (lane&15);
  int k  = kt*32 + ((lane>>4)<<3) + j;
  ((bf16*)(W + W_WB1))[i] = __float2bfloat16(W[W_WP + oc*2592 + k*27 + tap]);
}
__global__ __launch_bounds__(256) void k_packb2(float* __restrict__ W){
  int i = blockIdx.x*256 + threadIdx.x;
  if(i >= 27648) return;
  int j = i&7; int lane = (i>>3)&63; int frag = i>>9;
  int nt = frag&1; int tap = frag>>1;
  int oc = nt*16 + (lane&15);
  int ic = ((lane>>4)<<3) + j;
  ((bf16*)(W + W_WB2))[i] = __float2bfloat16(W[W_C1W + oc*864 + ic*27 + tap]);
}

// ---------------- i1 pre-conv (folded deconv+w1) -> NHWC, GN stats set0 ----------------
__global__ __launch_bounds__(256) void k_i1pre(const void* __restrict__ x, const float* __restrict__ W,
    bf16* __restrict__ out, float* __restrict__ stats_out, const float* __restrict__ flag)
{
  const int f = (int)flag[0];
  const int v = blockIdx.x*256 + threadIdx.x;
  const int b = blockIdx.y;
  const int xx = v%48, yy = (v/48)%48, zz = v/2304;
  const int par = ((zz&1)<<2) | ((yy&1)<<1) | (xx&1);
  const int vh = (zz>>1)*576 + (yy>>1)*24 + (xx>>1);
  float xr[64];
  #pragma unroll
  for(int c=0;c<64;c++) xr[c] = ldmix(x, (size_t)(b*64+c)*13824 + vh, f);
  const float* wp = W + W_W1P + par*3072;
  const float* bp = W + W_B1F;
  bf16* op = out + ((size_t)b*NVLL + v)*48;
  float ls = 0.f, lss = 0.f;
  #pragma unroll
  for(int o=0;o<48;o++){
    float acc = bp[o];
    #pragma unroll
    for(int c=0;c<64;c++) acc += wp[o*64+c]*xr[c];
    op[o] = __float2bfloat16(acc);
    ls += acc; lss += acc*acc;
    if((o&7)==7){
      #pragma unroll
      for(int sh=32;sh>=1;sh>>=1){ ls += __shfl_down(ls,sh); lss += __shfl_down(lss,sh); }
      if((threadIdx.x & 63)==0){
        int g = o>>3;
        atomicAdd(&stats_out[b*6+g], ls);
        atomicAdd(&stats_out[24 + b*6+g], lss);
      }
      ls = 0.f; lss = 0.f;
    }
  }
}

// ---------------- conv1x1 (+opt fused GN+leaky), NHWC internal, GN stats out -----------
template<int CIN, bool GNIN, bool MIXIN>
__global__ __launch_bounds__(256) void k_c1gn(const void* in, const float* __restrict__ W48,
    const float* __restrict__ bias, const float* __restrict__ gamma, const float* __restrict__ beta,
    const float* __restrict__ stats_in, int set_in,
    bf16* out, float* stats_out, int set_out, const float* __restrict__ flag)
{
  const int f = MIXIN ? (int)flag[0] : 0;
  const int v = blockIdx.x*256 + threadIdx.x;
  const int b = blockIdx.y;
  float m[6], rs[6];
  if constexpr(GNIN){
    const float invN = 1.0f/(8.0f*(float)NV);
    #pragma unroll
    for(int g=0; g<6; g++){
      float s  = stats_in[set_in*48 + b*6 + g];
      float ss = stats_in[set_in*48 + 24 + b*6 + g];
      float mm = s*invN;
      float var = ss*invN - mm*mm;
      m[g] = mm; rs[g] = rsqrtf(var + 1e-5f);
    }
  }
  float inv[CIN];
  #pragma unroll
  for(int c=0;c<CIN;c++){
    float xv = MIXIN ? ldmix(in, ((size_t)(b*CIN+c))*NVLL + v, f)
                     : __bfloat162float(((const bf16*)in)[((size_t)b*NVLL + v)*48 + c]);
    if constexpr(GNIN){
      int g = c>>3;
      xv = (xv - m[g])*rs[g]*gamma[c] + beta[c];
      xv = xv < 0.f ? 0.1f*xv : xv;
    }
    inv[c] = xv;
  }
  bf16* op = out + ((size_t)b*NVLL + v)*48;
  float ls = 0.f, lss = 0.f;
  #pragma unroll
  for(int o=0;o<48;o++){
    float acc = bias[o];
    #pragma unroll
    for(int c=0;c<CIN;c++) acc += W48[o*CIN+c]*inv[c];
    op[o] = __float2bfloat16(acc);
    ls += acc; lss += acc*acc;
    if((o&7)==7){
      #pragma unroll
      for(int sh=32;sh>=1;sh>>=1){ ls += __shfl_down(ls,sh); lss += __shfl_down(lss,sh); }
      if((threadIdx.x & 63)==0){
        int g = o>>3;
        atomicAdd(&stats_out[set_out*48 + b*6+g], ls);
        atomicAdd(&stats_out[set_out*48 + 24 + b*6+g], lss);
      }
      ls = 0.f; lss = 0.f;
    }
  }
}

// ---------------- GN apply + leaky(0.1), NHWC in place ----------------
__global__ __launch_bounds__(256) void k_gn_apply(bf16* buf, const float* __restrict__ stats, int set,
    const float* __restrict__ gamma, const float* __restrict__ beta)
{
  size_t i = (size_t)blockIdx.x*256 + threadIdx.x;   // exact: 4*NV*48
  int c = (int)(i % 48);
  int b = (int)(i/(NVLL*48));
  int g = c>>3;
  const float invN = 1.0f/(8.0f*(float)NV);
  float s  = stats[set*48 + b*6+g];
  float ss = stats[set*48 + 24 + b*6+g];
  float m = s*invN; float var = ss*invN - m*m; float rs = rsqrtf(var + 1e-5f);
  float xv = __bfloat162float(buf[i]);
  xv = (xv - m)*rs*gamma[c] + beta[c];
  buf[i] = __float2bfloat16(xv < 0.f ? 0.1f*xv : xv);
}

// ---------------- pool 48^3 -> 6^3 on NHWC bf16 (block per (b,cell)) ----------------
__global__ __launch_bounds__(512) void k_pool2(const bf16* __restrict__ s0, const bf16* __restrict__ s1,
    float* __restrict__ d0, float* __restrict__ d1)
{
  const int which = blockIdx.y;
  const bf16* src = which ? s1 : s0;
  float*      dst = which ? d1 : d0;
  const int cell = blockIdx.x % 216, b = blockIdx.x/216;
  const int tid = threadIdx.x;
  const int cz=cell/36, cy=(cell/6)%6, cx=cell%6;
  const int dz=tid>>6, dy=(tid>>3)&7, dx=tid&7;
  const size_t vox = (size_t)(cz*8+dz)*2304 + (cy*8+dy)*48 + (cx*8+dx);
  const bf16* p = src + ((size_t)b*NVLL + vox)*48;
  float val[48];
  #pragma unroll
  for(int c=0;c<48;c++) val[c] = __bfloat162float(p[c]);
  __shared__ float rmax[8][48], rsum[8][48];
  const int wid=tid>>6, lane=tid&63;
  #pragma unroll
  for(int o=0;o<48;o++){
    float mx=val[o], sm=val[o];
    #pragma unroll
    for(int s=32;s>=1;s>>=1){ mx=fmaxf(mx,__shfl_xor(mx,s)); sm+=__shfl_xor(sm,s); }
    if(lane==0){ rmax[wid][o]=mx; rsum[wid][o]=sm; }
  }
  __syncthreads();
  if(tid<48){
    float mx=rmax[0][tid], sm=rsum[0][tid];
    #pragma unroll
    for(int w2=1;w2<8;w2++){ mx=fmaxf(mx,rmax[w2][tid]); sm+=rsum[w2][tid]; }
    dst[(size_t)(b*48+tid)*216 + cell] = mx + sm*(1.f/512.f);
  }
}

// ---------------- fused conv1x1(concat(xe, folded-x0)) + pool -> pkv -------------------
__global__ __launch_bounds__(512) void k_poolfuse(const void* __restrict__ xe, const void* __restrict__ x,
    const float* __restrict__ W, float* __restrict__ pkv, const float* __restrict__ flag)
{
  const int f = (int)flag[0];
  const int cell = blockIdx.x % 216;
  const int b = blockIdx.x / 216;
  const int tid = threadIdx.x;
  const int cz = cell/36, cy = (cell/6)%6, cx = cell%6;
  const int dz = tid>>6, dy = (tid>>3)&7, dx = tid&7;
  const int gz = cz*8+dz, gy = cy*8+dy, gx = cx*8+dx;
  const size_t voff = (size_t)gz*2304 + gy*48 + gx;
  const int par = ((gz&1)<<2) | ((gy&1)<<1) | (gx&1);
  const int vh = (gz>>1)*576 + (gy>>1)*24 + (gx>>1);
  float xev[32], xrv[64];
  #pragma unroll
  for(int c=0;c<32;c++) xev[c] = ldmix(xe, ((size_t)(b*32+c))*NVLL + voff, f);
  #pragma unroll
  for(int c=0;c<64;c++) xrv[c] = ldmix(x, (size_t)(b*64+c)*13824 + vh, f);
  const float* wf  = W + W_WF;
  const float* wfp = W + W_WFP + par*3072;
  const float* bff = W + W_BFF;
  __shared__ float rmax[8][48];
  __shared__ float rsum[8][48];
  const int wid = tid>>6, lane = tid&63;
  #pragma unroll
  for(int o=0;o<48;o++){
    float acc = bff[o];
    #pragma unroll
    for(int c=0;c<32;c++) acc += wf[o*64+c]*xev[c];
    #pragma unroll
    for(int c=0;c<64;c++) acc += wfp[o*64+c]*xrv[c];
    float mx = acc, sm = acc;
    #pragma unroll
    for(int s=32;s>=1;s>>=1){ mx = fmaxf(mx, __shfl_xor(mx,s)); sm += __shfl_xor(sm,s); }
    if(lane==0){ rmax[wid][o] = mx; rsum[wid][o] = sm; }
  }
  __syncthreads();
  if(tid < 48){
    float mx = rmax[0][tid], sm = rsum[0][tid];
    #pragma unroll
    for(int w2=1;w2<8;w2++){ mx = fmaxf(mx, rmax[w2][tid]); sm += rsum[w2][tid]; }
    pkv[((size_t)(b*48+tid))*216 + cell] = mx + sm*(1.f/512.f);
  }
}

// ---------------- linear cross-attention ----------------
__global__ __launch_bounds__(256) void k_attn(const float* __restrict__ p1, const float* __restrict__ p2,
    const float* __restrict__ pkv, const float* __restrict__ W, float* __restrict__ a1, float* __restrict__ a2)
{
  const int which = blockIdx.x, b = blockIdx.y;
  const float* wb = W + W_ATT + which*9408;
  const float* wq = wb;        const float* bq = wb+2304;
  const float* wk = wb+2352;   const float* bk = wb+4656;
  const float* wv = wb+4704;   const float* bv = wb+7008;
  const float* wo = wb+7056;   const float* bo = wb+9360;
  const float* q   = which ? p2 : p1;
  float*       aout= which ? a2 : a1;
  const float* kvb = pkv + (size_t)b*48*216;
  const float* qb  = q   + (size_t)b*48*216;
  __shared__ float kh[216*48];
  __shared__ float ctx[288];
  const int tid = threadIdx.x;

  if(tid < 216){
    float kvr[48];
    #pragma unroll
    for(int c=0;c<48;c++) kvr[c] = kvb[c*216 + tid];
    #pragma unroll
    for(int o=0;o<48;o++){
      float acc = bk[o];
      #pragma unroll
      for(int c=0;c<48;c++) acc += kvr[c]*wk[o*48+c];
      kh[tid*48+o] = acc;
    }
  }
  __syncthreads();
  if(tid < 48){
    float mx = -1e30f;
    for(int n=0;n<216;n++) mx = fmaxf(mx, kh[n*48+tid]);
    float s = 0.f;
    for(int n=0;n<216;n++){ float e = __expf(kh[n*48+tid]-mx); kh[n*48+tid] = e; s += e; }
    float inv = 1.f/s;
    for(int n=0;n<216;n++) kh[n*48+tid] *= inv;
  }
  __syncthreads();
  if(tid < 48){
    int h = tid/6, e = tid%6;
    float cacc[6] = {0,0,0,0,0,0};
    for(int n=0;n<216;n++){
      float vh = bv[h*6+e];
      #pragma unroll
      for(int c=0;c<48;c++) vh += kvb[c*216+n]*wv[(h*6+e)*48+c];
      #pragma unroll
      for(int d=0;d<6;d++) cacc[d] += kh[n*48 + h*6+d]*vh;
    }
    #pragma unroll
    for(int d=0;d<6;d++) ctx[(h*6+d)*6+e] = cacc[d];
  }
  __syncthreads();
  if(tid < 216){
    int n = tid;
    float qr[48];
    #pragma unroll
    for(int c=0;c<48;c++) qr[c] = qb[c*216 + n];
    float qh[48];
    #pragma unroll
    for(int o=0;o<48;o++){
      float acc = bq[o];
      #pragma unroll
      for(int c=0;c<48;c++) acc += qr[c]*wq[o*48+c];
      qh[o] = acc;
    }
    #pragma unroll
    for(int h=0;h<8;h++){
      float mx = qh[h*6];
      #pragma unroll
      for(int d=1;d<6;d++) mx = fmaxf(mx, qh[h*6+d]);
      float s = 0.f;
      #pragma unroll
      for(int d=0;d<6;d++){ float e = __expf(qh[h*6+d]-mx); qh[h*6+d] = e; s += e; }
      float inv = 1.f/s;
      #pragma unroll
      for(int d=0;d<6;d++) qh[h*6+d] *= inv;
    }
    float ov[48];
    #pragma unroll
    for(int h=0;h<8;h++){
      #pragma unroll
      for(int e=0;e<6;e++){
        float acc = 0.f;
        #pragma unroll
        for(int d=0;d<6;d++) acc += qh[h*6+d]*ctx[(h*6+d)*6+e];
        ov[h*6+e] = acc;
      }
    }
    #pragma unroll
    for(int o=0;o<48;o++){
      float acc = bo[o];
      #pragma unroll
      for(int c=0;c<48;c++) acc += ov[c]*wo[o*48+c];
      aout[((size_t)(b*48+o))*216 + n] = acc;
    }
  }
}

// ---------------- gate: i1 *= sig(up(a1)), i2 *= sig(up(a2)), NHWC in place ------------
__device__ inline void interp1(int u, int& i0, int& i1, float& t){
  float pos = u * (5.0f/47.0f);
  float f = floorf(pos);
  i0 = (int)f; if(i0 > 5) i0 = 5;
  i1 = i0+1 > 5 ? 5 : i0+1;
  t = pos - f; if(t < 0.f) t = 0.f; if(t > 1.f) t = 1.f;
}

__global__ __launch_bounds__(256) void k_gate(bf16* i1b, bf16* i2b,
    const float* __restrict__ a1, const float* __restrict__ a2)
{
  const int v = blockIdx.x*256 + threadIdx.x;
  const int b = blockIdx.y;
  const int x = v % 48, y = (v/48) % 48, z = v/2304;
  int xi0,xi1,yi0,yi1,zi0,zi1; float xt,yt,zt;
  interp1(x,xi0,xi1,xt); interp1(y,yi0,yi1,yt); interp1(z,zi0,zi1,zt);
  int off[8]; float cw[8];
  off[0]=zi0*36+yi0*6+xi0; cw[0]=(1-zt)*(1-yt)*(1-xt);
  off[1]=zi0*36+yi0*6+xi1; cw[1]=(1-zt)*(1-yt)*xt;
  off[2]=zi0*36+yi1*6+xi0; cw[2]=(1-zt)*yt*(1-xt);
  off[3]=zi0*36+yi1*6+xi1; cw[3]=(1-zt)*yt*xt;
  off[4]=zi1*36+yi0*6+xi0; cw[4]=zt*(1-yt)*(1-xt);
  off[5]=zi1*36+yi0*6+xi1; cw[5]=zt*(1-yt)*xt;
  off[6]=zi1*36+yi1*6+xi0; cw[6]=zt*yt*(1-xt);
  off[7]=zi1*36+yi1*6+xi1; cw[7]=zt*yt*xt;
  bf16* p1 = i1b + ((size_t)b*NVLL + v)*48;
  bf16* p2 = i2b + ((size_t)b*NVLL + v)*48;
  const float* A1b = a1 + (size_t)b*48*216;
  const float* A2b = a2 + (size_t)b*48*216;
  #pragma unroll 4
  for(int c=0;c<48;c++){
    float s = 0.f;
    #pragma unroll
    for(int k=0;k<8;k++) s += cw[k]*A1b[c*216+off[k]];
    s = 1.f/(1.f + __expf(-s));
    p1[c] = __float2bfloat16(s * __bfloat162float(p1[c]));
  }
  #pragma unroll 4
  for(int c=0;c<48;c++){
    float s = 0.f;
    #pragma unroll
    for(int k=0;k<8;k++) s += cw[k]*A2b[c*216+off[k]];
    s = 1.f/(1.f + __expf(-s));
    p2[c] = __float2bfloat16(s * __bfloat162float(p2[c]));
  }
}

// ---------------- MFMA implicit-GEMM 3x3x3 conv, one batch -----------------------------
// wave: 16-voxel x-run (M) x 32 oc (N=2 frags); K-loop: 27 taps x KT k-tiles of 32.
// A[m=lane&15][k=quad*8+j] direct NHWC loads; B pre-packed frag order.
template<int KT, bool TWO, bool USETB>
__global__ __launch_bounds__(256) void k_conv3m(
    const bf16* __restrict__ in0, const bf16* __restrict__ in1,
    const bf16* __restrict__ wb, const float* __restrict__ tb, const float* __restrict__ cb,
    bf16* __restrict__ outp, float* __restrict__ stato, int sOut, int bidx, int onhwc)
{
  const int tid = threadIdx.x;
  const int wid = tid>>6, lane = tid&63;
  const int run = blockIdx.x*4 + wid;          // 6912 runs
  const int x0 = (run%3)*16, y = (run/3)%48, z = run/144;
  const int m = lane&15, quad = lane>>4;
  const int CB = TWO ? 48 : 32;
  const int k0 = quad*8;
  const short8x* wb8 = (const short8x*)wb;
  const short8x zf = {0,0,0,0,0,0,0,0};

  f32x4 acc0 = {0.f,0.f,0.f,0.f};
  f32x4 acc1 = {0.f,0.f,0.f,0.f};

  for(int dz=0; dz<3; dz++){
    int zz = z + dz - 1;
    if(zz < 0 || zz >= 48) continue;
    for(int dy=0; dy<3; dy++){
      int yy = y + dy - 1;
      if(yy < 0 || yy >= 48) continue;
      #pragma unroll
      for(int dx=0; dx<3; dx++){
        int xx = x0 + m + dx - 1;
        bool ok = (xx >= 0 && xx < 48);
        int xc = xx < 0 ? 0 : (xx > 47 ? 47 : xx);
        int vox = zz*2304 + yy*48 + xc;
        int tap = dz*9 + dy*3 + dx;
        #pragma unroll
        for(int kt=0; kt<KT; kt++){
          int kk = kt*32 + k0;
          const bf16* src; int ch;
          if(TWO){ if(kk < 48){ src = in0; ch = kk; } else { src = in1; ch = kk-48; } }
          else    { src = in0; ch = kk; }
          short8x af = *(const short8x*)(src + (size_t)vox*CB + ch);
          if(!ok) af = zf;
          short8x b0 = wb8[ (size_t)((tap*KT + kt)*2 + 0)*64 + lane ];
          short8x b1 = wb8[ (size_t)((tap*KT + kt)*2 + 1)*64 + lane ];
          acc0 = __builtin_amdgcn_mfma_f32_16x16x32_bf16(af, b0, acc0, 0,0,0);
          acc1 = __builtin_amdgcn_mfma_f32_16x16x32_bf16(af, b1, acc1, 0,0,0);
        }
      }
    }
  }

  const int oc0 = m, oc1 = 16 + m;              // D: col=lane&15 -> oc
  float s0=0.f, ss0=0.f, s1=0.f, ss1=0.f;
  #pragma unroll
  for(int r=0;r<4;r++){
    int mv = quad*4 + r;                        // D: row=(lane>>4)*4+reg -> voxel in run
    int xr = x0 + mv;
    float b0v = cb[oc0], b1v = cb[oc1];
    if constexpr(USETB){
      #pragma unroll
      for(int t=0;t<27;t++){
        int tdz = t/9, tdy = (t/3)%3, tdx = t%3;
        int zz = z+tdz-1, yy = y+tdy-1, xx = xr+tdx-1;
        if(zz>=0 && zz<48 && yy>=0 && yy<48 && xx>=0 && xx<48){
          b0v += tb[t*32+oc0]; b1v += tb[t*32+oc1];
        }
      }
    }
    float v0 = acc0[r] + b0v;
    float v1 = acc1[r] + b1v;
    size_t vox = (size_t)z*2304 + y*48 + xr;
    if(onhwc){
      outp[vox*32 + oc0] = __float2bfloat16(v0);
      outp[vox*32 + oc1] = __float2bfloat16(v1);
    } else {
      outp[(size_t)oc0*NVLL + vox] = __float2bfloat16(v0);
      outp[(size_t)oc1*NVLL + vox] = __float2bfloat16(v1);
    }
    s0 += v0; ss0 += v0*v0; s1 += v1; ss1 += v1*v1;
  }
  s0 += __shfl_xor(s0,16); ss0 += __shfl_xor(ss0,16); s1 += __shfl_xor(s1,16); ss1 += __shfl_xor(ss1,16);
  s0 += __shfl_xor(s0,32); ss0 += __shfl_xor(ss0,32); s1 += __shfl_xor(s1,32); ss1 += __shfl_xor(ss1,32);
  if(quad==0){
    atomicAdd(&stato[sOut + bidx*32 + oc0], s0);
    atomicAdd(&stato[sOut + 128 + bidx*32 + oc0], ss0);
    atomicAdd(&stato[sOut + bidx*32 + oc1], s1);
    atomicAdd(&stato[sOut + 128 + bidx*32 + oc1], ss1);
  }
}

// ---------------- IN + leaky(0.01) on h1 (NHWC, 4 scattered regions) -------------------
struct P4 { bf16* p[4]; };
__global__ __launch_bounds__(256) void k_inleak(P4 h1, const float* __restrict__ stats){
  int i = blockIdx.x*256 + threadIdx.x;        // exact: 4*NV*32
  int b = i/(NV*32);
  int j = i - b*(NV*32);
  int c = j & 31;
  const float invN = 1.f/(float)NV;
  float s  = stats[192 + b*32 + c];
  float ss = stats[192 + 128 + b*32 + c];
  float m = s*invN; float var = ss*invN - m*m; float rs = rsqrtf(var + 1e-5f);
  float xv = (__bfloat162float(h1.p[b][j]) - m)*rs;
  h1.p[b][j] = __float2bfloat16(xv < 0.f ? 0.01f*xv : xv);
}

// ---------------- final IN + leaky(0.01): h2 slabs (NCHW) -> d_out ----------------
__global__ __launch_bounds__(256) void k_in_final(P4 h2, const float* __restrict__ stats,
    void* out, const float* __restrict__ flag)
{
  const int f = (int)flag[0];
  int i = blockIdx.x*256 + threadIdx.x;        // exact: 4*32*NV
  int b = i/(NV*32);
  int j = i - b*(NV*32);                       // = c*NV + v
  int c = j/NV;
  const float invN = 1.f/(float)NV;
  float s  = stats[448 + b*32 + c];
  float ss = stats[448 + 128 + b*32 + c];
  float m = s*invN; float var = ss*invN - m*m; float rs = rsqrtf(var + 1e-5f);
  float xv = (__bfloat162float(h2.p[b][j]) - m)*rs;
  xv = xv < 0.f ? 0.01f*xv : xv;
  if(f) ((float*)out)[i] = xv;
  else  ((bf16*)out)[i]  = __float2bfloat16(xv);
}

// ==========================================================================
extern "C" void kernel_launch(void* const* d_in, const int* in_sizes, int n_in,
                              void* d_out, int out_size, void* d_ws, size_t ws_size,
                              hipStream_t stream)
{
  (void)in_sizes; (void)n_in; (void)out_size; (void)ws_size;
  char* base = (char*)d_ws;
  const void* x  = d_in[0];
  const void* xe = d_in[1];

  float* SM  = (float*)base;
  float* P1  = SM + SM_P1;
  float* P2  = SM + SM_P2;
  float* PKV = SM + SM_PKV;
  float* A1  = SM + SM_A1;
  float* A2  = SM + SM_A2;
  float* ST  = SM + SM_ST;
  float* W   = SM + SM_W;
  float* FL  = SM + SM_FL;
  bf16*  O1  = (bf16*)(base + BOFF_O1);
  bf16*  O2  = (bf16*)(base + BOFF_O2);

  // h1 per-batch bases (NHWC 32ch): b0 -> spare; b1..3 overlay dead o1(0..2)
  P4 H1, H2;
  H1.p[0] = (bf16*)(base + BOFF_SP);
  H1.p[1] = (bf16*)(base + BOFF_O1);
  H1.p[2] = (bf16*)(base + BOFF_O1 + SLOT48);
  H1.p[3] = (bf16*)(base + BOFF_O1 + 2*SLOT48);
  // h2 per-batch slabs (NCHW within slab) overlay dead o2(b)
  for(int b=0;b<4;b++) H2.p[b] = (bf16*)(base + BOFF_O2 + (size_t)b*SLOT48);

  k_detect<<<1, 256, 0, stream>>>(xe, FL);
  k_zero<<<3, 256, 0, stream>>>(ST);

  PtrTab pt;
  for(int i=0;i<36;i++) pt.p[i] = d_in[i+2];
  k_prep<<<(W_TOTAL+255)/256, 256, 0, stream>>>(pt, W, FL);
  k_fold <<<193, 256, 0, stream>>>(W);
  k_fold2<<<328, 256, 0, stream>>>(W);
  k_packb1<<<324, 256, 0, stream>>>(W);
  k_packb2<<<108, 256, 0, stream>>>(W);

  const float* gam = W + W_GNG;
  const float* bet = W + W_GNB;

  // i1 branch -> O1 (NHWC)
  k_i1pre<<<dim3(432,4), 256, 0, stream>>>(x, W, O1, ST, FL);
  k_c1gn<48,true ,false><<<dim3(432,4),256,0,stream>>>(O1, W+W_W3, W+W_B3, gam, bet, ST, 0, O1, ST, 1, FL);
  k_gn_apply<<<21233664/256, 256, 0, stream>>>(O1, ST, 1, gam, bet);

  // i2 branch -> O2 (NHWC)
  k_c1gn<32,false,true ><<<dim3(432,4),256,0,stream>>>(xe, W+W_W2, W+W_B2, gam, bet, ST, 0, O2, ST, 2, FL);
  k_c1gn<48,true ,false><<<dim3(432,4),256,0,stream>>>(O2, W+W_W4, W+W_B4, gam, bet, ST, 2, O2, ST, 3, FL);
  k_gn_apply<<<21233664/256, 256, 0, stream>>>(O2, ST, 3, gam, bet);

  // pools + attention
  k_pool2<<<dim3(864,2), 512, 0, stream>>>(O1, O2, P1, P2);
  k_poolfuse<<<864, 512, 0, stream>>>(xe, x, W, PKV, FL);
  k_attn<<<dim3(2,4), 256, 0, stream>>>(P1, P2, PKV, W, A1, A2);

  // gate i1,i2 in place -> o1,o2
  k_gate<<<dim3(432,4), 256, 0, stream>>>(O1, O2, A1, A2);

  // conv#1 (folded with Wfin): 96ch NHWC -> h1 (NHWC 32ch), IN stats @192
  const bf16* WB1 = (const bf16*)(W + W_WB1);
  const bf16* WB2 = (const bf16*)(W + W_WB2);
  for(int b=0;b<4;b++){
    const bf16* o1b = O1 + (size_t)b*48*NVLL;
    const bf16* o2b = O2 + (size_t)b*48*NVLL;
    k_conv3m<3,true,true><<<1728, 256, 0, stream>>>(o1b, o2b, WB1, W+W_TB, W+W_C0B,
                                                    H1.p[b], ST, 192, b, 1);
  }
  // IN+leaky on h1
  k_inleak<<<55296, 256, 0, stream>>>(H1, ST);

  // conv#2: 32ch NHWC -> h2 (NCHW slab), IN stats @448
  for(int b=0;b<4;b++){
    k_conv3m<1,false,false><<<1728, 256, 0, stream>>>(H1.p[b], nullptr, WB2, nullptr, W+W_C1B,
                                                      H2.p[b], ST, 448, b, 0);
  }
  // final IN + leaky -> d_out
  k_in_final<<<55296, 256, 0, stream>>>(H2, ST, d_out, FL);
}